// Round 14
// baseline (258.826 us; speedup 1.0000x reference)
//
#include <hip/hip_runtime.h>
#include <math.h>

#define H 64
#define HK 8
#define HD 64
#define DM 1024
#define WINDOW 128
#define GQA (H / HK)
#define Bv 2
#define Sv 1024

typedef _Float16 f16;
typedef __attribute__((ext_vector_type(8))) _Float16 f16x8;
typedef __attribute__((ext_vector_type(4))) _Float16 f16x4;
typedef __attribute__((ext_vector_type(4))) float f32x4;

__device__ __forceinline__ void gload_lds16(const void* g, void* l) {
    __builtin_amdgcn_global_load_lds((const __attribute__((address_space(1))) void*)g,
                                     (__attribute__((address_space(3))) void*)l, 16, 0, 0);
}

// ---------------------------------------------------------------------------
// QKV GEMM: 128x160 tile, BK=64, 256 thr = 4 waves (2x2, each 64x80 = 4x5
// MFMA 16x16x32). Grid 512 blocks; XCD supertile swizzle (R11-validated).
// ---------------------------------------------------------------------------
__global__ __launch_bounds__(256, 2) void qkv_gemm(const f16* __restrict__ xh,
                                                   const f16* __restrict__ wqkv,
                                                   const float* __restrict__ bqkv,
                                                   f16* __restrict__ qh,
                                                   f16* __restrict__ khb,
                                                   f16* __restrict__ vtb) {
    __shared__ __align__(16) f16 As[128 * 64];
    __shared__ __align__(16) f16 Bs[160 * 64];

    const int t    = threadIdx.x;
    const int lane = t & 63;
    const int w    = t >> 6;
    const int lr   = lane & 15;
    const int quad = lane >> 4;
    const int srow = lane >> 3;
    const int gsw  = lane & 7;

    // supertile swizzle: id -> (bx, by)
    const int id    = blockIdx.x;
    const int s     = id >> 6;
    const int local = id & 63;
    const int bx    = (s & 3) * 8 + (local & 7);
    const int by    = (s >> 2) * 8 + (local >> 3);

    const int m0   = by * 128;
    const int n0   = bx * 160;
    const int wm   = w >> 1;
    const int wn   = w & 1;

    f32x4 acc[4][5] = {};

    for (int k0 = 0; k0 < DM; k0 += 64) {
#pragma unroll
        for (int i = 0; i < 4; ++i) {
            const int row = (w * 4 + i) * 8 + srow;
            const int g   = gsw ^ (row & 7);
            gload_lds16(xh + (size_t)(m0 + row) * DM + k0 + g * 8, As + (w * 4 + i) * 512);
        }
#pragma unroll
        for (int i = 0; i < 5; ++i) {
            const int row = (w * 5 + i) * 8 + srow;
            const int g   = gsw ^ (row & 7);
            gload_lds16(wqkv + (size_t)(n0 + row) * DM + k0 + g * 8, Bs + (w * 5 + i) * 512);
        }
        __syncthreads();
#pragma unroll
        for (int ks = 0; ks < 2; ++ks) {
            f16x8 af[4], bf[5];
#pragma unroll
            for (int tt = 0; tt < 4; ++tt) {
                const int m  = wm * 64 + tt * 16 + lr;
                const int ca = (ks * 4 + quad) ^ (m & 7);
                af[tt] = *(const f16x8*)(As + m * 64 + ca * 8);
            }
#pragma unroll
            for (int tt = 0; tt < 5; ++tt) {
                const int n  = wn * 80 + tt * 16 + lr;
                const int cb = (ks * 4 + quad) ^ (n & 7);
                bf[tt] = *(const f16x8*)(Bs + n * 64 + cb * 8);
            }
#pragma unroll
            for (int i = 0; i < 4; ++i)
#pragma unroll
                for (int j = 0; j < 5; ++j)
                    acc[i][j] = __builtin_amdgcn_mfma_f32_16x16x32_f16(af[i], bf[j], acc[i][j], 0, 0, 0);
        }
        __syncthreads();
    }

#pragma unroll
    for (int i = 0; i < 4; ++i) {
        const int grow = m0 + wm * 64 + i * 16 + quad * 4;
#pragma unroll
        for (int j = 0; j < 5; ++j) {
            const int gcb  = n0 + wn * 80 + j * 16;
            const int gcol = gcb + lr;
            const float bz = bqkv[gcol];
            if (gcb < 4096) {            // Q (pre-scaled by 1/8)
#pragma unroll
                for (int r = 0; r < 4; ++r)
                    qh[(size_t)(grow + r) * 4096 + gcol] = (f16)((acc[i][j][r] + bz) * 0.125f);
            } else if (gcb < 4608) {     // K: khb[((b*8+hk)*1024+s)*64+d]
                const int lc = gcol - 4096;
                const size_t base = (size_t)(grow >> 10) * 524288 + (size_t)(lc >> 6) * 65536
                                  + (size_t)(grow & 1023) * 64 + (lc & 63);
#pragma unroll
                for (int r = 0; r < 4; ++r)
                    khb[base + (size_t)r * 64] = (f16)(acc[i][j][r] + bz);
            } else {                     // V^T: vtb[((b*8+hk)*64+d)*1024+s]
                const int lc = gcol - 4608;
                const size_t base = ((size_t)(grow >> 10) * 512 + lc) * 1024 + (grow & 1023);
                f16x4 o;
#pragma unroll
                for (int r = 0; r < 4; ++r) o[r] = (f16)(acc[i][j][r] + bz);
                *(f16x4*)(vtb + base) = o;
            }
        }
    }
}

// ---------------------------------------------------------------------------
// O-projection split-K x4 with FUSED reduction: each block stores its fp32
// partial tile (dwordx4 streams -- R13 showed per-element atomics are 2x
// slower), then release-fences and bumps a per-tile counter; the LAST of the
// 4 kz blocks for a tile sums the 4 partials + bias into out. With the
// supertile swizzle, all 4 kz blocks of a tile are congruent mod 8 -> same
// XCD -> partial reads are L2-local. __threadfence() = agent-scope
// (buffer_wbl2/inv sc1) -> correct regardless of XCD mapping.
// Counters zeroed by attn_mfma (kernel-boundary ordering).
// ---------------------------------------------------------------------------
__global__ __launch_bounds__(256, 2) void o_gemm_fused(const f16* __restrict__ oh,
                                                       const f16* __restrict__ woh,
                                                       float* __restrict__ partials,
                                                       int* __restrict__ ctr,
                                                       const float* __restrict__ bo,
                                                       float* __restrict__ out) {
    __shared__ __align__(16) f16 As[128 * 64];
    __shared__ __align__(16) f16 Bs[128 * 64];
    __shared__ int done;

    const int t    = threadIdx.x;
    const int lane = t & 63;
    const int w    = t >> 6;
    const int lr   = lane & 15;
    const int quad = lane >> 4;
    const int srow = lane >> 3;
    const int gsw  = lane & 7;

    // supertile swizzle: id -> (kz, bx, by)
    const int id    = blockIdx.x;
    const int kz    = id >> 7;
    const int r_    = id & 127;
    const int st    = r_ >> 6;
    const int local = r_ & 63;
    const int by    = st * 8 + (local & 7);
    const int bx    = local >> 3;

    const int m0   = by * 128;
    const int n0   = bx * 128;
    const int wm   = w >> 1;
    const int wn   = w & 1;

    const f16* A = oh  + (size_t)kz * 1024;
    const f16* W = woh + (size_t)kz * 1024;
    float* P = partials + (size_t)kz * 2097152;

    f32x4 acc[4][4] = {};

    for (int k0 = 0; k0 < 1024; k0 += 64) {
#pragma unroll
        for (int i = 0; i < 4; ++i) {
            const int row = (w * 4 + i) * 8 + srow;
            const int g   = gsw ^ (row & 7);
            gload_lds16(A + (size_t)(m0 + row) * 4096 + k0 + g * 8, As + (w * 4 + i) * 512);
            gload_lds16(W + (size_t)(n0 + row) * 4096 + k0 + g * 8, Bs + (w * 4 + i) * 512);
        }
        __syncthreads();
#pragma unroll
        for (int ks = 0; ks < 2; ++ks) {
            f16x8 af[4], bf[4];
#pragma unroll
            for (int tt = 0; tt < 4; ++tt) {
                const int m  = wm * 64 + tt * 16 + lr;
                const int ca = (ks * 4 + quad) ^ (m & 7);
                af[tt] = *(const f16x8*)(As + m * 64 + ca * 8);
                const int n  = wn * 64 + tt * 16 + lr;
                const int cb = (ks * 4 + quad) ^ (n & 7);
                bf[tt] = *(const f16x8*)(Bs + n * 64 + cb * 8);
            }
#pragma unroll
            for (int i = 0; i < 4; ++i)
#pragma unroll
                for (int j = 0; j < 4; ++j)
                    acc[i][j] = __builtin_amdgcn_mfma_f32_16x16x32_f16(af[i], bf[j], acc[i][j], 0, 0, 0);
        }
        __syncthreads();
    }

#pragma unroll
    for (int i = 0; i < 4; ++i) {
        const int grow = m0 + wm * 64 + i * 16 + quad * 4;
#pragma unroll
        for (int j = 0; j < 4; ++j) {
            const int gcol = n0 + wn * 64 + j * 16 + lr;
#pragma unroll
            for (int r = 0; r < 4; ++r)
                P[(size_t)(grow + r) * 1024 + gcol] = acc[i][j][r];
        }
    }

    // ---- tile-completion counter; last block reduces ----
    const int tile = by * 8 + bx;            // 0..127
    __threadfence();                          // release partial stores (agent)
    if (t == 0) done = atomicAdd(&ctr[tile], 1);
    __syncthreads();
    if (done == 3) {
        __threadfence();                      // acquire others' partials
        const float4* p = (const float4*)partials;
        const float4* b4 = (const float4*)bo;
        // tile = 128 rows x 32 float4-cols = 4096 float4; 16 per thread
#pragma unroll
        for (int ii = 0; ii < 16; ++ii) {
            const int idx = ii * 256 + t;
            const int rr  = idx >> 5;
            const int cc  = idx & 31;
            const size_t g = (size_t)(m0 + rr) * 256 + (n0 >> 2) + cc;
            float4 a0 = p[g];
            float4 a1 = p[g + 524288];
            float4 a2 = p[g + 1048576];
            float4 a3 = p[g + 1572864];
            float4 bz = b4[(n0 >> 2) + cc];
            float4 o;
            o.x = a0.x + a1.x + a2.x + a3.x + bz.x;
            o.y = a0.y + a1.y + a2.y + a3.y + bz.y;
            o.z = a0.z + a1.z + a2.z + a3.z + bz.z;
            o.w = a0.w + a1.w + a2.w + a3.w + bz.w;
            ((float4*)out)[g] = o;
        }
    }
}

// ---------------------------------------------------------------------------
// Fused fp32->f16 conversion + fused-bias build.
// ---------------------------------------------------------------------------
#define C_X  524288
#define C_WQ 1572864
#define C_WK 1703936
#define C_WV 1835008
#define C_WO 2883584

__global__ __launch_bounds__(256) void convert_all(const float* __restrict__ x,
                                                   const float* __restrict__ Wq,
                                                   const float* __restrict__ Wk,
                                                   const float* __restrict__ Wv,
                                                   const float* __restrict__ Wo,
                                                   const float* __restrict__ bq,
                                                   const float* __restrict__ bk,
                                                   const float* __restrict__ bv,
                                                   f16* __restrict__ xh,
                                                   f16* __restrict__ wqkv,
                                                   f16* __restrict__ woh,
                                                   float* __restrict__ bqkv) {
    const int i = blockIdx.x * 256 + threadIdx.x;
    if (i < 5120) {
        float v;
        if (i < 4096)      v = bq[i];
        else if (i < 4608) v = bk[i - 4096];
        else               v = bv[i - 4608];
        bqkv[i] = v;
    }
    const float* src;
    f16* dst;
    int off;
    if (i < C_X)       { src = x;  dst = xh;              off = i; }
    else if (i < C_WQ) { src = Wq; dst = wqkv;            off = i - C_X; }
    else if (i < C_WK) { src = Wk; dst = wqkv + 4194304;  off = i - C_WQ; }
    else if (i < C_WV) { src = Wv; dst = wqkv + 4718592;  off = i - C_WK; }
    else               { src = Wo; dst = woh;             off = i - C_WV; }
    const float4 v = ((const float4*)src)[off];
    f16x4 o;
    o[0] = (f16)v.x; o[1] = (f16)v.y; o[2] = (f16)v.z; o[3] = (f16)v.w;
    *(f16x4*)(dst + (size_t)off * 4) = o;
}

// ---------------------------------------------------------------------------
// MFMA flash attention v3 (validated R10) + split-K counter zero-init.
// launch_bounds(256,2): (256,3) spilled (R9: 70 MB scratch writes).
// ---------------------------------------------------------------------------
#define VTS 200

__global__ __launch_bounds__(256, 2) void attn_mfma(const f16* __restrict__ qh,
                                                    const f16* __restrict__ khb,
                                                    const f16* __restrict__ vtb,
                                                    const float* __restrict__ sinks,
                                                    f16* __restrict__ oh,
                                                    int* __restrict__ ctr) {
    __shared__ __align__(16) f16 Kl[192 * 64];
    __shared__ __align__(16) f16 Vt[64 * VTS];

    const int t  = threadIdx.x;
    const int q0 = blockIdx.x * 64;
    const int hk = blockIdx.y >> 1;
    const int hh = blockIdx.y & 1;
    const int b  = blockIdx.z;
    const int c0 = q0 - WINDOW;

    // zero the 128 split-K tile counters (kernel completes before o_gemm)
    if (blockIdx.x == 0 && blockIdx.y == 0 && blockIdx.z == 0 && t < 128)
        ctr[t] = 0;

    const int lane = t & 63;
    const int w    = t >> 6;
    const int lr   = lane & 15;
    const int quad = lane >> 4;
    const int srow = lane >> 3;
    const int gsw  = lane & 7;

    const f16* kg = khb + (size_t)(b * HK + hk) * Sv * HD;
    const f16* vg = vtb + (size_t)(b * HK + hk) * HD * Sv;

#pragma unroll
    for (int it = 0; it < 6; ++it) {
        const int row = (w * 6 + it) * 8 + srow;      // 0..191
        const int g   = gsw ^ (row & 7);
        int j = c0 + row;
        if (j < 0) j = 0;                             // garbage -> masked
        gload_lds16(kg + (size_t)j * HD + g * 8, Kl + (w * 6 + it) * 512);
    }
#pragma unroll
    for (int it = 0; it < 6; ++it) {
        const int i = it * 256 + t;                   // 0..1535
        const int d = i / 24, c = i % 24;
        int j0 = c0 + c * 8;
        if (j0 < 0) j0 = 0;                           // garbage -> masked
        const f16x8 val = *(const f16x8*)(vg + (size_t)d * Sv + j0);
        *(f16x8*)(&Vt[d * VTS + c * 8]) = val;
    }
    __syncthreads();

    const int h = hk * GQA + hh * 4 + w;

    f16x8 qf[4][2];
#pragma unroll
    for (int mt = 0; mt < 4; ++mt) {
        const f16* qrow = qh + (size_t)(b * Sv + q0 + mt * 16 + lr) * 4096 + h * 64;
#pragma unroll
        for (int ks = 0; ks < 2; ++ks)
            qf[mt][ks] = *(const f16x8*)(qrow + ks * 32 + quad * 8);
    }
    const float sk   = sinks[h];
    const int   smin = (c0 < 0) ? -c0 : 0;

    f32x4 O[4][4] = {};          // O^T tiles [mt][dt]: row d=quad*4+r, col q=lr
    float lsum[4] = {0.f, 0.f, 0.f, 0.f};

#pragma unroll
    for (int nt = 0; nt < 12; ++nt) {
        f16x8 kf[2];
#pragma unroll
        for (int ks = 0; ks < 2; ++ks)
            kf[ks] = *(const f16x8*)(&Kl[(nt * 16 + lr) * 64 + (((ks * 4 + quad) ^ (lr & 7)) * 8)]);
        f16x4 vf[4];
#pragma unroll
        for (int dt = 0; dt < 4; ++dt)
            vf[dt] = *(const f16x4*)(&Vt[(dt * 16 + lr) * VTS + nt * 16 + quad * 4]);

#pragma unroll
        for (int mt = 0; mt < 4; ++mt) {
            if (nt < mt || nt > mt + 8) continue;     // tile fully masked
            f32x4 S = {};
#pragma unroll
            for (int ks = 0; ks < 2; ++ks)
                S = __builtin_amdgcn_mfma_f32_16x16x32_f16(kf[ks], qf[mt][ks], S, 0, 0, 0);
            f16x4 pf;
#pragma unroll
            for (int r = 0; r < 4; ++r) {
                const int sl = nt * 16 + quad * 4 + r;
                const int mq = mt * 16 + lr;
                const bool ok = (sl > mq) && (sl <= mq + WINDOW) && (sl >= smin);
                const float p = ok ? __expf(S[r]) : 0.f;
                lsum[mt] += p;
                pf[r] = (f16)p;
            }
#pragma unroll
            for (int dt = 0; dt < 4; ++dt)
                O[mt][dt] = __builtin_amdgcn_mfma_f32_16x16x16f16(vf[dt], pf, O[mt][dt], 0, 0, 0);
        }
    }

    const float esk = __expf(sk);
#pragma unroll
    for (int mt = 0; mt < 4; ++mt) {
        float l = lsum[mt];
        l += __shfl_xor(l, 16, 64);
        l += __shfl_xor(l, 32, 64);
        lsum[mt] = 1.f / (l + esk);        // sink column joins denominator
    }

#pragma unroll
    for (int mt = 0; mt < 4; ++mt) {
        const float inv = lsum[mt];
        f16* orow = oh + (size_t)(b * Sv + q0 + mt * 16 + lr) * 4096 + h * 64;
#pragma unroll
        for (int dt = 0; dt < 4; ++dt) {
            f16x4 ov;
#pragma unroll
            for (int r = 0; r < 4; ++r) ov[r] = (f16)(O[mt][dt][r] * inv);
            *(f16x4*)(orow + dt * 16 + quad * 4) = ov;
        }
    }
}

// ---------------------------------------------------------------------------
extern "C" void kernel_launch(void* const* d_in, const int* in_sizes, int n_in,
                              void* d_out, int out_size, void* d_ws, size_t ws_size,
                              hipStream_t stream) {
    const float* x     = (const float*)d_in[0];
    const float* Wq    = (const float*)d_in[1];
    const float* bq    = (const float*)d_in[2];
    const float* Wk    = (const float*)d_in[3];
    const float* bk    = (const float*)d_in[4];
    const float* Wv    = (const float*)d_in[5];
    const float* bv    = (const float*)d_in[6];
    const float* Wo    = (const float*)d_in[7];
    const float* bo    = (const float*)d_in[8];
    const float* sinks = (const float*)d_in[9];
    float* out = (float*)d_out;

    f16* xh   = (f16*)d_ws;                    // 2,097,152
    f16* wqkv = xh + 2097152;                  // 5,242,880
    f16* qh   = wqkv + 5242880;                // 8,388,608
    f16* khb  = qh + 8388608;                  // 1,048,576  [B][HK][S][HD]
    f16* vtb  = khb + 1048576;                 // 1,048,576  [B][HK][HD][S]
    f16* woh  = vtb + 1048576;                 // 4,194,304  LIVE at o_gemm
    f16* oh   = woh + 4194304;                 // 8,388,608  LIVE at o_gemm
    float* bqkv = (float*)(oh + 8388608);      // 5120 fp32
    int*   ctr  = (int*)(bqkv + 5120);         // 128 tile counters
    float* partials = (float*)d_ws;            // 32 MB, aliases dead prefix

    convert_all<<<dim3(C_WO / 256), dim3(256), 0, stream>>>(
        x, Wq, Wk, Wv, Wo, bq, bk, bv, xh, wqkv, woh, bqkv);

    qkv_gemm<<<dim3(512), dim3(256), 0, stream>>>(xh, wqkv, bqkv, qh, khb, vtb);

    attn_mfma<<<dim3(Sv / 64, HK * 2, Bv), dim3(256), 0, stream>>>(
        qh, khb, vtb, sinks, oh, ctr);

    o_gemm_fused<<<dim3(512), dim3(256), 0, stream>>>(oh, woh, partials, ctr, bo, out);
}

// Round 15
// 172.603 us; speedup vs baseline: 1.4995x; 1.4995x over previous
//
#include <hip/hip_runtime.h>
#include <math.h>

#define H 64
#define HK 8
#define HD 64
#define DM 1024
#define WINDOW 128
#define GQA (H / HK)
#define Bv 2
#define Sv 1024

typedef _Float16 f16;
typedef __attribute__((ext_vector_type(8))) _Float16 f16x8;
typedef __attribute__((ext_vector_type(4))) _Float16 f16x4;
typedef __attribute__((ext_vector_type(4))) float f32x4;

__device__ __forceinline__ void gload_lds16(const void* g, void* l) {
    __builtin_amdgcn_global_load_lds((const __attribute__((address_space(1))) void*)g,
                                     (__attribute__((address_space(3))) void*)l, 16, 0, 0);
}

// ---------------------------------------------------------------------------
// QKV GEMM: 128x160 tile, BK=64, 256 thr = 4 waves (2x2, each 64x80 = 4x5
// MFMA 16x16x32). Grid 512 blocks; XCD supertile swizzle (R11-validated).
// (256,2): R12 showed (256,3) neutral; R9 showed attn spills at 3.
// ---------------------------------------------------------------------------
__global__ __launch_bounds__(256, 2) void qkv_gemm(const f16* __restrict__ xh,
                                                   const f16* __restrict__ wqkv,
                                                   const float* __restrict__ bqkv,
                                                   f16* __restrict__ qh,
                                                   f16* __restrict__ khb,
                                                   f16* __restrict__ vtb) {
    __shared__ __align__(16) f16 As[128 * 64];
    __shared__ __align__(16) f16 Bs[160 * 64];

    const int t    = threadIdx.x;
    const int lane = t & 63;
    const int w    = t >> 6;
    const int lr   = lane & 15;
    const int quad = lane >> 4;
    const int srow = lane >> 3;
    const int gsw  = lane & 7;

    // supertile swizzle: id -> (bx, by); id%8 = XCD slot
    const int id    = blockIdx.x;
    const int s     = id >> 6;
    const int local = id & 63;
    const int bx    = (s & 3) * 8 + (local & 7);
    const int by    = (s >> 2) * 8 + (local >> 3);

    const int m0   = by * 128;
    const int n0   = bx * 160;
    const int wm   = w >> 1;
    const int wn   = w & 1;

    f32x4 acc[4][5] = {};

    for (int k0 = 0; k0 < DM; k0 += 64) {
#pragma unroll
        for (int i = 0; i < 4; ++i) {
            const int row = (w * 4 + i) * 8 + srow;
            const int g   = gsw ^ (row & 7);
            gload_lds16(xh + (size_t)(m0 + row) * DM + k0 + g * 8, As + (w * 4 + i) * 512);
        }
#pragma unroll
        for (int i = 0; i < 5; ++i) {
            const int row = (w * 5 + i) * 8 + srow;
            const int g   = gsw ^ (row & 7);
            gload_lds16(wqkv + (size_t)(n0 + row) * DM + k0 + g * 8, Bs + (w * 5 + i) * 512);
        }
        __syncthreads();
#pragma unroll
        for (int ks = 0; ks < 2; ++ks) {
            f16x8 af[4], bf[5];
#pragma unroll
            for (int tt = 0; tt < 4; ++tt) {
                const int m  = wm * 64 + tt * 16 + lr;
                const int ca = (ks * 4 + quad) ^ (m & 7);
                af[tt] = *(const f16x8*)(As + m * 64 + ca * 8);
            }
#pragma unroll
            for (int tt = 0; tt < 5; ++tt) {
                const int n  = wn * 80 + tt * 16 + lr;
                const int cb = (ks * 4 + quad) ^ (n & 7);
                bf[tt] = *(const f16x8*)(Bs + n * 64 + cb * 8);
            }
#pragma unroll
            for (int i = 0; i < 4; ++i)
#pragma unroll
                for (int j = 0; j < 5; ++j)
                    acc[i][j] = __builtin_amdgcn_mfma_f32_16x16x32_f16(af[i], bf[j], acc[i][j], 0, 0, 0);
        }
        __syncthreads();
    }

#pragma unroll
    for (int i = 0; i < 4; ++i) {
        const int grow = m0 + wm * 64 + i * 16 + quad * 4;
#pragma unroll
        for (int j = 0; j < 5; ++j) {
            const int gcb  = n0 + wn * 80 + j * 16;
            const int gcol = gcb + lr;
            const float bz = bqkv[gcol];
            if (gcb < 4096) {            // Q (pre-scaled by 1/8)
#pragma unroll
                for (int r = 0; r < 4; ++r)
                    qh[(size_t)(grow + r) * 4096 + gcol] = (f16)((acc[i][j][r] + bz) * 0.125f);
            } else if (gcb < 4608) {     // K: khb[((b*8+hk)*1024+s)*64+d]
                const int lc = gcol - 4096;
                const size_t base = (size_t)(grow >> 10) * 524288 + (size_t)(lc >> 6) * 65536
                                  + (size_t)(grow & 1023) * 64 + (lc & 63);
#pragma unroll
                for (int r = 0; r < 4; ++r)
                    khb[base + (size_t)r * 64] = (f16)(acc[i][j][r] + bz);
            } else {                     // V^T: vtb[((b*8+hk)*64+d)*1024+s]
                const int lc = gcol - 4608;
                const size_t base = ((size_t)(grow >> 10) * 512 + lc) * 1024 + (grow & 1023);
                f16x4 o;
#pragma unroll
                for (int r = 0; r < 4; ++r) o[r] = (f16)(acc[i][j][r] + bz);
                *(f16x4*)(vtb + base) = o;
            }
        }
    }
}

// ---------------------------------------------------------------------------
// O-projection split-K x4: 128x128 tile, f16 partials (halves partial HBM
// traffic vs fp32; one f16 round per partial ~2e-4 abs err, harmless).
// Grid 512, supertile swizzle. R13/R14 showed atomics and fence-fused
// reductions both lose; kernel-boundary reduce is the validated structure.
// ---------------------------------------------------------------------------
__global__ __launch_bounds__(256, 2) void o_gemm_split(const f16* __restrict__ oh,
                                                       const f16* __restrict__ woh,
                                                       f16* __restrict__ partials) {
    __shared__ __align__(16) f16 As[128 * 64];
    __shared__ __align__(16) f16 Bs[128 * 64];

    const int t    = threadIdx.x;
    const int lane = t & 63;
    const int w    = t >> 6;
    const int lr   = lane & 15;
    const int quad = lane >> 4;
    const int srow = lane >> 3;
    const int gsw  = lane & 7;

    // supertile swizzle: id -> (kz, bx, by)
    const int id    = blockIdx.x;
    const int kz    = id >> 7;
    const int r_    = id & 127;
    const int st    = r_ >> 6;
    const int local = r_ & 63;
    const int by    = st * 8 + (local & 7);
    const int bx    = local >> 3;

    const int m0   = by * 128;
    const int n0   = bx * 128;
    const int wm   = w >> 1;
    const int wn   = w & 1;

    const f16* A = oh  + (size_t)kz * 1024;
    const f16* W = woh + (size_t)kz * 1024;
    f16* P = partials + (size_t)kz * 2097152;

    f32x4 acc[4][4] = {};

    for (int k0 = 0; k0 < 1024; k0 += 64) {
#pragma unroll
        for (int i = 0; i < 4; ++i) {
            const int row = (w * 4 + i) * 8 + srow;
            const int g   = gsw ^ (row & 7);
            gload_lds16(A + (size_t)(m0 + row) * 4096 + k0 + g * 8, As + (w * 4 + i) * 512);
            gload_lds16(W + (size_t)(n0 + row) * 4096 + k0 + g * 8, Bs + (w * 4 + i) * 512);
        }
        __syncthreads();
#pragma unroll
        for (int ks = 0; ks < 2; ++ks) {
            f16x8 af[4], bf[4];
#pragma unroll
            for (int tt = 0; tt < 4; ++tt) {
                const int m  = wm * 64 + tt * 16 + lr;
                const int ca = (ks * 4 + quad) ^ (m & 7);
                af[tt] = *(const f16x8*)(As + m * 64 + ca * 8);
                const int n  = wn * 64 + tt * 16 + lr;
                const int cb = (ks * 4 + quad) ^ (n & 7);
                bf[tt] = *(const f16x8*)(Bs + n * 64 + cb * 8);
            }
#pragma unroll
            for (int i = 0; i < 4; ++i)
#pragma unroll
                for (int j = 0; j < 4; ++j)
                    acc[i][j] = __builtin_amdgcn_mfma_f32_16x16x32_f16(af[i], bf[j], acc[i][j], 0, 0, 0);
        }
        __syncthreads();
    }

#pragma unroll
    for (int i = 0; i < 4; ++i) {
        const int grow = m0 + wm * 64 + i * 16 + quad * 4;
#pragma unroll
        for (int j = 0; j < 4; ++j) {
            const int gcol = n0 + wn * 64 + j * 16 + lr;
#pragma unroll
            for (int r = 0; r < 4; ++r)
                P[(size_t)(grow + r) * 1024 + gcol] = (f16)acc[i][j][r];
        }
    }
}

// out = p0+p1+p2+p3 + bo ; f16 partials, 8 cols per thread (f16x8 reads,
// 2x float4 writes). Grid 1024 blocks.
__global__ __launch_bounds__(256) void reduce4h(const f16* __restrict__ pf,
                                                const float* __restrict__ bo,
                                                float* __restrict__ out) {
    const int i   = blockIdx.x * 256 + threadIdx.x;   // 0..262143
    const int row = i >> 7;
    const int c8  = (i & 127) << 3;
    const size_t base = (size_t)row * 1024 + c8;
    const f16x8 a0 = *(const f16x8*)(pf + base);
    const f16x8 a1 = *(const f16x8*)(pf + base + 2097152);
    const f16x8 a2 = *(const f16x8*)(pf + base + 4194304);
    const f16x8 a3 = *(const f16x8*)(pf + base + 6291456);
    const float4 bz0 = ((const float4*)bo)[c8 >> 2];
    const float4 bz1 = ((const float4*)bo)[(c8 >> 2) + 1];
    const float bb[8] = {bz0.x, bz0.y, bz0.z, bz0.w, bz1.x, bz1.y, bz1.z, bz1.w};
    float r[8];
#pragma unroll
    for (int j = 0; j < 8; ++j)
        r[j] = (float)a0[j] + (float)a1[j] + (float)a2[j] + (float)a3[j] + bb[j];
    float4 o0 = {r[0], r[1], r[2], r[3]};
    float4 o1 = {r[4], r[5], r[6], r[7]};
    ((float4*)out)[base >> 2] = o0;
    ((float4*)out)[(base >> 2) + 1] = o1;
}

// ---------------------------------------------------------------------------
// Fused fp32->f16 conversion + fused-bias build.
// ---------------------------------------------------------------------------
#define C_X  524288
#define C_WQ 1572864
#define C_WK 1703936
#define C_WV 1835008
#define C_WO 2883584

__global__ __launch_bounds__(256) void convert_all(const float* __restrict__ x,
                                                   const float* __restrict__ Wq,
                                                   const float* __restrict__ Wk,
                                                   const float* __restrict__ Wv,
                                                   const float* __restrict__ Wo,
                                                   const float* __restrict__ bq,
                                                   const float* __restrict__ bk,
                                                   const float* __restrict__ bv,
                                                   f16* __restrict__ xh,
                                                   f16* __restrict__ wqkv,
                                                   f16* __restrict__ woh,
                                                   float* __restrict__ bqkv) {
    const int i = blockIdx.x * 256 + threadIdx.x;
    if (i < 5120) {
        float v;
        if (i < 4096)      v = bq[i];
        else if (i < 4608) v = bk[i - 4096];
        else               v = bv[i - 4608];
        bqkv[i] = v;
    }
    const float* src;
    f16* dst;
    int off;
    if (i < C_X)       { src = x;  dst = xh;              off = i; }
    else if (i < C_WQ) { src = Wq; dst = wqkv;            off = i - C_X; }
    else if (i < C_WK) { src = Wk; dst = wqkv + 4194304;  off = i - C_WQ; }
    else if (i < C_WV) { src = Wv; dst = wqkv + 4718592;  off = i - C_WK; }
    else               { src = Wo; dst = woh;             off = i - C_WV; }
    const float4 v = ((const float4*)src)[off];
    f16x4 o;
    o[0] = (f16)v.x; o[1] = (f16)v.y; o[2] = (f16)v.z; o[3] = (f16)v.w;
    *(f16x4*)(dst + (size_t)off * 4) = o;
}

// ---------------------------------------------------------------------------
// MFMA flash attention v3 (validated R10/R11). Block = 4 waves = 4 GQA heads
// of one (b,hk,q0). S^T = mfma(a=K, b=Q); P feeds PV from registers.
// launch_bounds(256,2): (256,3) spilled (R9: 70 MB scratch writes).
// ---------------------------------------------------------------------------
#define VTS 200

__global__ __launch_bounds__(256, 2) void attn_mfma(const f16* __restrict__ qh,
                                                    const f16* __restrict__ khb,
                                                    const f16* __restrict__ vtb,
                                                    const float* __restrict__ sinks,
                                                    f16* __restrict__ oh) {
    __shared__ __align__(16) f16 Kl[192 * 64];
    __shared__ __align__(16) f16 Vt[64 * VTS];

    const int t  = threadIdx.x;
    const int q0 = blockIdx.x * 64;
    const int hk = blockIdx.y >> 1;
    const int hh = blockIdx.y & 1;
    const int b  = blockIdx.z;
    const int c0 = q0 - WINDOW;

    const int lane = t & 63;
    const int w    = t >> 6;
    const int lr   = lane & 15;
    const int quad = lane >> 4;
    const int srow = lane >> 3;
    const int gsw  = lane & 7;

    const f16* kg = khb + (size_t)(b * HK + hk) * Sv * HD;
    const f16* vg = vtb + (size_t)(b * HK + hk) * HD * Sv;

#pragma unroll
    for (int it = 0; it < 6; ++it) {
        const int row = (w * 6 + it) * 8 + srow;      // 0..191
        const int g   = gsw ^ (row & 7);
        int j = c0 + row;
        if (j < 0) j = 0;                             // garbage -> masked
        gload_lds16(kg + (size_t)j * HD + g * 8, Kl + (w * 6 + it) * 512);
    }
#pragma unroll
    for (int it = 0; it < 6; ++it) {
        const int i = it * 256 + t;                   // 0..1535
        const int d = i / 24, c = i % 24;
        int j0 = c0 + c * 8;
        if (j0 < 0) j0 = 0;                           // garbage -> masked
        const f16x8 val = *(const f16x8*)(vg + (size_t)d * Sv + j0);
        *(f16x8*)(&Vt[d * VTS + c * 8]) = val;
    }
    __syncthreads();

    const int h = hk * GQA + hh * 4 + w;

    f16x8 qf[4][2];
#pragma unroll
    for (int mt = 0; mt < 4; ++mt) {
        const f16* qrow = qh + (size_t)(b * Sv + q0 + mt * 16 + lr) * 4096 + h * 64;
#pragma unroll
        for (int ks = 0; ks < 2; ++ks)
            qf[mt][ks] = *(const f16x8*)(qrow + ks * 32 + quad * 8);
    }
    const float sk   = sinks[h];
    const int   smin = (c0 < 0) ? -c0 : 0;

    f32x4 O[4][4] = {};          // O^T tiles [mt][dt]: row d=quad*4+r, col q=lr
    float lsum[4] = {0.f, 0.f, 0.f, 0.f};

#pragma unroll
    for (int nt = 0; nt < 12; ++nt) {
        f16x8 kf[2];
#pragma unroll
        for (int ks = 0; ks < 2; ++ks)
            kf[ks] = *(const f16x8*)(&Kl[(nt * 16 + lr) * 64 + (((ks * 4 + quad) ^ (lr & 7)) * 8)]);
        f16x4 vf[4];
#pragma unroll
        for (int dt = 0; dt < 4; ++dt)
            vf[dt] = *(const f16x4*)(&Vt[(dt * 16 + lr) * VTS + nt * 16 + quad * 4]);

#pragma unroll
        for (int mt = 0; mt < 4; ++mt) {
            if (nt < mt || nt > mt + 8) continue;     // tile fully masked
            f32x4 S = {};
#pragma unroll
            for (int ks = 0; ks < 2; ++ks)
                S = __builtin_amdgcn_mfma_f32_16x16x32_f16(kf[ks], qf[mt][ks], S, 0, 0, 0);
            f16x4 pf;
#pragma unroll
            for (int r = 0; r < 4; ++r) {
                const int sl = nt * 16 + quad * 4 + r;
                const int mq = mt * 16 + lr;
                const bool ok = (sl > mq) && (sl <= mq + WINDOW) && (sl >= smin);
                const float p = ok ? __expf(S[r]) : 0.f;
                lsum[mt] += p;
                pf[r] = (f16)p;
            }
#pragma unroll
            for (int dt = 0; dt < 4; ++dt)
                O[mt][dt] = __builtin_amdgcn_mfma_f32_16x16x16f16(vf[dt], pf, O[mt][dt], 0, 0, 0);
        }
    }

    const float esk = __expf(sk);
#pragma unroll
    for (int mt = 0; mt < 4; ++mt) {
        float l = lsum[mt];
        l += __shfl_xor(l, 16, 64);
        l += __shfl_xor(l, 32, 64);
        lsum[mt] = 1.f / (l + esk);        // sink column joins denominator
    }

#pragma unroll
    for (int mt = 0; mt < 4; ++mt) {
        const float inv = lsum[mt];
        f16* orow = oh + (size_t)(b * Sv + q0 + mt * 16 + lr) * 4096 + h * 64;
#pragma unroll
        for (int dt = 0; dt < 4; ++dt) {
            f16x4 ov;
#pragma unroll
            for (int r = 0; r < 4; ++r) ov[r] = (f16)(O[mt][dt][r] * inv);
            *(f16x4*)(orow + dt * 16 + quad * 4) = ov;
        }
    }
}

// ---------------------------------------------------------------------------
extern "C" void kernel_launch(void* const* d_in, const int* in_sizes, int n_in,
                              void* d_out, int out_size, void* d_ws, size_t ws_size,
                              hipStream_t stream) {
    const float* x     = (const float*)d_in[0];
    const float* Wq    = (const float*)d_in[1];
    const float* bq    = (const float*)d_in[2];
    const float* Wk    = (const float*)d_in[3];
    const float* bk    = (const float*)d_in[4];
    const float* Wv    = (const float*)d_in[5];
    const float* bv    = (const float*)d_in[6];
    const float* Wo    = (const float*)d_in[7];
    const float* bo    = (const float*)d_in[8];
    const float* sinks = (const float*)d_in[9];
    float* out = (float*)d_out;

    f16* xh   = (f16*)d_ws;                    // 2,097,152
    f16* wqkv = xh + 2097152;                  // 5,242,880
    f16* qh   = wqkv + 5242880;                // 8,388,608
    f16* khb  = qh + 8388608;                  // 1,048,576  [B][HK][S][HD]
    f16* vtb  = khb + 1048576;                 // 1,048,576  [B][HK][HD][S]
    f16* woh  = vtb + 1048576;                 // 4,194,304  LIVE at o_gemm
    f16* oh   = woh + 4194304;                 // 8,388,608  LIVE at o_gemm
    float* bqkv = (float*)(oh + 8388608);      // 5120 fp32
    f16* partials = (f16*)d_ws;                // 4 x 2M f16 = 16 MB, aliases
                                               // dead prefix (xh..qh = 30.5 MB)

    convert_all<<<dim3(C_WO / 256), dim3(256), 0, stream>>>(
        x, Wq, Wk, Wv, Wo, bq, bk, bv, xh, wqkv, woh, bqkv);

    qkv_gemm<<<dim3(512), dim3(256), 0, stream>>>(xh, wqkv, bqkv, qh, khb, vtb);

    attn_mfma<<<dim3(Sv / 64, HK * 2, Bv), dim3(256), 0, stream>>>(qh, khb, vtb, sinks, oh);

    o_gemm_split<<<dim3(512), dim3(256), 0, stream>>>(oh, woh, partials);
    reduce4h<<<dim3(1024), dim3(256), 0, stream>>>(partials, bo, out);
}